// Round 5
// baseline (172.983 us; speedup 1.0000x reference)
//
#include <hip/hip_runtime.h>
#include <hip/hip_bf16.h>
#include <hip/hip_fp16.h>

// B=2, S=2048, DIM=1024, H=16, DH=64.
// CONTRACT (corrected round 5): output d_out is FLOAT32 (reference dtype).
// Inputs: dtype runtime-detected (bf16 / f32 / f16) and canonicalized to bf16 in ws.
//
// ws layout (bf16 elems):
//  Xc @ 0 | Wq @ 4194304 | Wk @ 5242880 | Wv @ 6291456
//  bq @ 7340032  bk @ 7341056  bv @ 7342080  ga @ 7343104  be @ 7344128
//  Qw @ 7345152 | Kw @ 11539456 | VTw @ 15733760 | Ow @ 19928064 | end 24122368
//  flags (4 ints) @ byte 48244736: [0]=dtype(0 bf16,1 f32,2 f16)

typedef float f32x4 __attribute__((ext_vector_type(4)));
typedef __bf16 bf16x8 __attribute__((ext_vector_type(8)));
typedef unsigned short u16;
typedef u16 u16x4 __attribute__((ext_vector_type(4)));
typedef u16 u16x8 __attribute__((ext_vector_type(8)));
typedef unsigned int u32;

static __device__ __forceinline__ float bf2f(u16 u) {
  u32 x = ((u32)u) << 16;
  return __builtin_bit_cast(float, x);
}
static __device__ __forceinline__ u16 f2bf(float f) {
  __hip_bfloat16 h = __float2bfloat16(f);
  return __builtin_bit_cast(u16, h);
}

// ---------------- signal (host-detected problems) ----------------
__global__ __launch_bounds__(256) void fill_signal(float* __restrict__ out, float v) {
  int i = blockIdx.x * 256 + threadIdx.x;
  if (i < 4194304) out[i] = v;
}

// ---------------- dtype detection (3-way) ----------------
// maxexp>=160 over u16 words -> f32 (low mantissa halves have uniform bits).
// else: var of exp-field ~2-10 for bf16 N(0,1), ~100+ for f16 -> threshold 60.
__global__ __launch_bounds__(256) void detect_dtype(const u16* __restrict__ emb,
                                                    int* __restrict__ flags) {
  const int tid = threadIdx.x;
  u32 maxexp = 0;
  float sum = 0.f, sumsq = 0.f;
  for (int i = 0; i < 64; i++) {
    u16 u = emb[tid * 64 + i];
    u32 e = (u >> 7) & 0xFF;
    maxexp = maxexp > e ? maxexp : e;
    float ef = (float)e;
    sum += ef; sumsq += ef * ef;
  }
  for (int m = 1; m < 64; m <<= 1) {
    u32 o = (u32)__shfl_xor((int)maxexp, m);
    maxexp = maxexp > o ? maxexp : o;
    sum += __shfl_xor(sum, m);
    sumsq += __shfl_xor(sumsq, m);
  }
  __shared__ u32 rm[4];
  __shared__ float rs[4], rq[4];
  if ((tid & 63) == 0) { rm[tid >> 6] = maxexp; rs[tid >> 6] = sum; rq[tid >> 6] = sumsq; }
  __syncthreads();
  if (tid == 0) {
    u32 mx = rm[0]; float s = rs[0], q = rq[0];
    for (int i = 1; i < 4; i++) {
      mx = mx > rm[i] ? mx : rm[i];
      s += rs[i]; q += rq[i];
    }
    int fl;
    if (mx >= 160) fl = 1;                       // f32
    else {
      float mean = s * (1.0f / 16384.0f);
      float var = q * (1.0f / 16384.0f) - mean * mean;
      fl = (var > 60.0f) ? 2 : 0;                // f16 : bf16
    }
    flags[0] = fl;
  }
}

// ---------------- canonicalize inputs to bf16 ----------------
__global__ __launch_bounds__(256) void convert_inputs(
    const void* __restrict__ s0, const void* __restrict__ s1,
    const void* __restrict__ s2, const void* __restrict__ s3,
    const void* __restrict__ s4, const void* __restrict__ s5,
    const void* __restrict__ s6, const void* __restrict__ s7,
    const void* __restrict__ s8,
    u16* __restrict__ ws, const int* __restrict__ flags)
{
  const int t = blockIdx.x * 256 + threadIdx.x;  // unit = 8 elems
  if (t >= 918144) return;
  const void* src; size_t dstoff; int local;
  if      (t < 524288) { src = s0; dstoff = 0;       local = t; }
  else if (t < 655360) { src = s1; dstoff = 4194304; local = t - 524288; }
  else if (t < 786432) { src = s2; dstoff = 5242880; local = t - 655360; }
  else if (t < 917504) { src = s3; dstoff = 6291456; local = t - 786432; }
  else if (t < 917632) { src = s4; dstoff = 7340032; local = t - 917504; }
  else if (t < 917760) { src = s5; dstoff = 7341056; local = t - 917632; }
  else if (t < 917888) { src = s6; dstoff = 7342080; local = t - 917760; }
  else if (t < 918016) { src = s7; dstoff = 7343104; local = t - 917888; }
  else                 { src = s8; dstoff = 7344128; local = t - 918016; }
  const int fl = flags[0];
  u16x8 o;
  if (fl == 1) {
    const float* fp = (const float*)src + (size_t)local * 8;
#pragma unroll
    for (int i = 0; i < 8; i++) o[i] = f2bf(fp[i]);
  } else if (fl == 2) {
    u16x8 hv = *((const u16x8*)src + local);
#pragma unroll
    for (int i = 0; i < 8; i++) {
      u16 tmp = hv[i];
      float v = (float)__builtin_bit_cast(_Float16, tmp);
      o[i] = f2bf(v);
    }
  } else {
    o = *((const u16x8*)src + local);
  }
  *(u16x8*)&ws[dstoff + (size_t)local * 8] = o;
}

// ---------------- fused QKV projection ----------------
// out[i,j] = sum_k X[i,k]*W[j,k] + bias[j]. 128x128 tile, BK=32, 4 waves 2x2,
// register-staged double buffer, padded LDS stride 40 elems.
__global__ __launch_bounds__(256) void qkv_gemm(
    const u16* __restrict__ ws,
    u16* __restrict__ Qo, u16* __restrict__ Ko, u16* __restrict__ VTo)
{
  __shared__ __align__(16) u16 As[128 * 40];
  __shared__ __align__(16) u16 Bs[128 * 40];

  const int z = blockIdx.z;
  const u16* X    = ws;
  const u16* W    = ws + 4194304 + (size_t)z * 1048576;
  const u16* bias = ws + 7340032 + (size_t)z * 1024;

  const int tid = threadIdx.x;
  const int lane = tid & 63, wid = tid >> 6;
  const int wm = wid >> 1, wn = wid & 1;
  const int g = lane >> 4, cc = lane & 15;
  const int bm = blockIdx.x * 128, bn = blockIdx.y * 128;

  u16x8 ra[2], rb[2];
  const int row0 = tid >> 2,         sl0 = tid & 3;
  const int row1 = (tid + 256) >> 2, sl1 = tid & 3;

  f32x4 acc[4][4] = {};

  ra[0] = *(const u16x8*)&X[(size_t)(bm + row0) * 1024 + sl0 * 8];
  ra[1] = *(const u16x8*)&X[(size_t)(bm + row1) * 1024 + sl1 * 8];
  rb[0] = *(const u16x8*)&W[(size_t)(bn + row0) * 1024 + sl0 * 8];
  rb[1] = *(const u16x8*)&W[(size_t)(bn + row1) * 1024 + sl1 * 8];

  for (int kt = 0; kt < 1024; kt += 32) {
    __syncthreads();
    *(u16x8*)&As[row0 * 40 + sl0 * 8] = ra[0];
    *(u16x8*)&As[row1 * 40 + sl1 * 8] = ra[1];
    *(u16x8*)&Bs[row0 * 40 + sl0 * 8] = rb[0];
    *(u16x8*)&Bs[row1 * 40 + sl1 * 8] = rb[1];
    __syncthreads();

    if (kt + 32 < 1024) {
      int kn = kt + 32;
      ra[0] = *(const u16x8*)&X[(size_t)(bm + row0) * 1024 + kn + sl0 * 8];
      ra[1] = *(const u16x8*)&X[(size_t)(bm + row1) * 1024 + kn + sl1 * 8];
      rb[0] = *(const u16x8*)&W[(size_t)(bn + row0) * 1024 + kn + sl0 * 8];
      rb[1] = *(const u16x8*)&W[(size_t)(bn + row1) * 1024 + kn + sl1 * 8];
    }

    bf16x8 a[4], b[4];
#pragma unroll
    for (int mf = 0; mf < 4; mf++)
      a[mf] = *(const bf16x8*)&As[(wm * 64 + mf * 16 + cc) * 40 + g * 8];
#pragma unroll
    for (int nf = 0; nf < 4; nf++)
      b[nf] = *(const bf16x8*)&Bs[(wn * 64 + nf * 16 + cc) * 40 + g * 8];
#pragma unroll
    for (int mf = 0; mf < 4; mf++)
#pragma unroll
      for (int nf = 0; nf < 4; nf++)
        acc[mf][nf] = __builtin_amdgcn_mfma_f32_16x16x32_bf16(a[mf], b[nf], acc[mf][nf], 0, 0, 0);
  }

  // C/D layout H1 (hardware-confirmed by round-3/4 probe): col=lane&15, row=(lane>>4)*4+reg
#pragma unroll
  for (int mf = 0; mf < 4; mf++) {
#pragma unroll
    for (int nf = 0; nf < 4; nf++) {
#pragma unroll
      for (int r = 0; r < 4; r++) {
        int i = bm + wm * 64 + mf * 16 + g * 4 + r;
        int j = bn + wn * 64 + nf * 16 + cc;
        u16 o = f2bf(acc[mf][nf][r] + bf2f(bias[j]));
        int b_ = i >> 11, s_ = i & 2047, h_ = j >> 6, d_ = j & 63;
        size_t hb = (size_t)(b_ * 16 + h_) * (2048 * 64);
        if (z == 2)      VTo[hb + (size_t)d_ * 2048 + s_] = o;   // V transposed
        else { u16* dst = z ? Ko : Qo; dst[hb + (size_t)s_ * 64 + d_] = o; }
      }
    }
  }
}

// ---------------- flash attention ----------------
// block = (64 q-rows, bh); 4 waves, wave owns 16 q-rows. On-device-verified
// (round 4 chk_attn green) against scalar softmax reference.
__global__ __launch_bounds__(256) void attn(
    const u16* __restrict__ Q, const u16* __restrict__ K,
    const u16* __restrict__ VT, u16* __restrict__ O)
{
  __shared__ __align__(16) u16 Ks[64 * 72];
  __shared__ __align__(16) u16 Vs[64 * 72];
  __shared__ float Sf[4][16 * 72];
  __shared__ __align__(16) u16 Pt[4][16 * 72];
  __shared__ float Al[4][16];
  __shared__ float Ll[4][16];

  const int tid = threadIdx.x, lane = tid & 63, wid = tid >> 6;
  const int g = lane >> 4, cc = lane & 15;
  const int srow = lane >> 2, sq = lane & 3;
  const int bh = blockIdx.y;
  const int q0 = blockIdx.x * 64 + wid * 16;
  const size_t base = (size_t)bh * 131072;

  bf16x8 qf[2];
#pragma unroll
  for (int kc = 0; kc < 2; kc++)
    qf[kc] = *(const bf16x8*)&Q[base + (size_t)(q0 + cc) * 64 + kc * 32 + g * 8];

  f32x4 o_acc[4] = {};
  float m_s = -1e30f, l_s = 0.f;

  const int kr0 = tid >> 3,         ks0 = tid & 7;
  const int kr1 = (tid + 256) >> 3, ks1 = tid & 7;

  u16x8 rk[2], rv[2];
  rk[0] = *(const u16x8*)&K [base + (size_t)kr0 * 64 + ks0 * 8];
  rk[1] = *(const u16x8*)&K [base + (size_t)kr1 * 64 + ks1 * 8];
  rv[0] = *(const u16x8*)&VT[base + (size_t)kr0 * 2048 + ks0 * 8];
  rv[1] = *(const u16x8*)&VT[base + (size_t)kr1 * 2048 + ks1 * 8];

  for (int kv0 = 0; kv0 < 2048; kv0 += 64) {
    __syncthreads();
    *(u16x8*)&Ks[kr0 * 72 + ks0 * 8] = rk[0];
    *(u16x8*)&Ks[kr1 * 72 + ks1 * 8] = rk[1];
    *(u16x8*)&Vs[kr0 * 72 + ks0 * 8] = rv[0];
    *(u16x8*)&Vs[kr1 * 72 + ks1 * 8] = rv[1];
    __syncthreads();

    if (kv0 + 64 < 2048) {
      int kn = kv0 + 64;
      rk[0] = *(const u16x8*)&K [base + (size_t)(kn + kr0) * 64 + ks0 * 8];
      rk[1] = *(const u16x8*)&K [base + (size_t)(kn + kr1) * 64 + ks1 * 8];
      rv[0] = *(const u16x8*)&VT[base + (size_t)kr0 * 2048 + kn + ks0 * 8];
      rv[1] = *(const u16x8*)&VT[base + (size_t)kr1 * 2048 + kn + ks1 * 8];
    }

    f32x4 s_acc[4];
#pragma unroll
    for (int f = 0; f < 4; f++) {
      f32x4 sa = {};
#pragma unroll
      for (int kc = 0; kc < 2; kc++) {
        bf16x8 kf = *(const bf16x8*)&Ks[(f * 16 + cc) * 72 + (kc * 4 + g) * 8];
        sa = __builtin_amdgcn_mfma_f32_16x16x32_bf16(qf[kc], kf, sa, 0, 0, 0);
      }
      s_acc[f] = sa;
    }

#pragma unroll
    for (int f = 0; f < 4; f++)
#pragma unroll
      for (int r = 0; r < 4; r++)
        Sf[wid][(g * 4 + r) * 72 + f * 16 + cc] = s_acc[f][r];
    __syncthreads();

    float sv[16];
#pragma unroll
    for (int c = 0; c < 16; c++) sv[c] = Sf[wid][srow * 72 + sq * 16 + c];
    float mx = sv[0];
#pragma unroll
    for (int c = 1; c < 16; c++) mx = fmaxf(mx, sv[c]);
    mx = fmaxf(mx, __shfl_xor(mx, 1));
    mx = fmaxf(mx, __shfl_xor(mx, 2));
    float nm = fmaxf(m_s, mx * 0.125f);
    float alpha = __expf(m_s - nm);
    float rs = 0.f;
#pragma unroll
    for (int c = 0; c < 16; c++) {
      float pv = __expf(sv[c] * 0.125f - nm);
      Pt[wid][srow * 72 + sq * 16 + c] = f2bf(pv);
      rs += pv;
    }
    rs += __shfl_xor(rs, 1);
    rs += __shfl_xor(rs, 2);
    l_s = l_s * alpha + rs;
    m_s = nm;
    if (sq == 0) Al[wid][srow] = alpha;
    __syncthreads();

#pragma unroll
    for (int r = 0; r < 4; r++) {
      float a = Al[wid][g * 4 + r];
#pragma unroll
      for (int f = 0; f < 4; f++) o_acc[f][r] *= a;
    }

    bf16x8 pf[2];
#pragma unroll
    for (int kc = 0; kc < 2; kc++)
      pf[kc] = *(const bf16x8*)&Pt[wid][cc * 72 + kc * 32 + g * 8];
#pragma unroll
    for (int f = 0; f < 4; f++) {
#pragma unroll
      for (int kc = 0; kc < 2; kc++) {
        bf16x8 vf = *(const bf16x8*)&Vs[(f * 16 + cc) * 72 + (kc * 4 + g) * 8];
        o_acc[f] = __builtin_amdgcn_mfma_f32_16x16x32_bf16(pf[kc], vf, o_acc[f], 0, 0, 0);
      }
    }
  }

  if (sq == 0) Ll[wid][srow] = l_s;
  __syncthreads();

#pragma unroll
  for (int r = 0; r < 4; r++) {
    float li = Ll[wid][g * 4 + r];
#pragma unroll
    for (int f = 0; f < 4; f++)
      O[base + (size_t)(q0 + g * 4 + r) * 64 + f * 16 + cc] = f2bf(o_acc[f][r] / li);
  }
}

// ---------------- residual + LayerNorm -> FLOAT32 output ----------------
// z[b,s,:] is the CONTIGUOUS O slice at (b*16 + s>>7)*131072 + (s&127)*1024
__global__ __launch_bounds__(256) void ln_gather(
    const u16* __restrict__ emb, const u16* __restrict__ Og,
    const u16* __restrict__ gamma, const u16* __restrict__ beta,
    float* __restrict__ out)
{
  const int row = blockIdx.x;            // b*2048 + s
  const int b = row >> 11, s = row & 2047;
  const int tid = threadIdx.x;
  const size_t ebase = (size_t)row * 1024;
  const size_t obase = ((size_t)(b * 16 + (s >> 7)) << 17) + (size_t)(s & 127) * 1024;
  const int c0 = tid * 4;

  u16x4 ev = *(const u16x4*)&emb[ebase + c0];
  u16x4 zv = *(const u16x4*)&Og[obase + c0];
  float x[4];
  float sum = 0.f, sq = 0.f;
#pragma unroll
  for (int i = 0; i < 4; i++) {
    x[i] = bf2f(ev[i]) + bf2f(zv[i]);
    sum += x[i];
    sq  += x[i] * x[i];
  }
#pragma unroll
  for (int m = 1; m < 64; m <<= 1) { sum += __shfl_xor(sum, m); sq += __shfl_xor(sq, m); }

  __shared__ float red[8];
  const int lane = tid & 63, wid = tid >> 6;
  if (lane == 0) { red[wid] = sum; red[4 + wid] = sq; }
  __syncthreads();
  sum = red[0] + red[1] + red[2] + red[3];
  sq  = red[4] + red[5] + red[6] + red[7];

  float mu  = sum * (1.0f / 1024.0f);
  float var = sq * (1.0f / 1024.0f) - mu * mu;
  float rstd = rsqrtf(var + 1e-5f);

  u16x4 gv  = *(const u16x4*)&gamma[c0];
  u16x4 btv = *(const u16x4*)&beta[c0];
  f32x4 ov;
#pragma unroll
  for (int i = 0; i < 4; i++)
    ov[i] = (x[i] - mu) * rstd * bf2f(gv[i]) + bf2f(btv[i]);
  *(f32x4*)&out[ebase + c0] = ov;
}

extern "C" void kernel_launch(void* const* d_in, const int* in_sizes, int n_in,
                              void* d_out, int out_size, void* d_ws, size_t ws_size,
                              hipStream_t stream) {
  (void)out_size;
  const size_t NEED = 48244736 + 16;
  if (ws_size < NEED) {
    fill_signal<<<16384, 256, 0, stream>>>((float*)d_out, 3000.0f);
    return;
  }
  if (n_in != 9) {
    fill_signal<<<16384, 256, 0, stream>>>((float*)d_out, 2600.0f);
    return;
  }
  const int expect[9] = {4194304, 1048576, 1024, 1048576, 1024, 1048576, 1024, 1024, 1024};
  for (int i = 0; i < 9; i++) {
    if (in_sizes[i] != expect[i]) {
      fill_signal<<<16384, 256, 0, stream>>>((float*)d_out, 2500.0f);
      return;
    }
  }

  u16* ws = (u16*)d_ws;
  int* flags = (int*)((char*)d_ws + 48244736);

  const size_t SZ = (size_t)4194304;
  u16* Qw  = ws + 7345152;
  u16* Kw  = Qw + SZ;
  u16* VTw = Kw + SZ;
  u16* Ow  = VTw + SZ;

  detect_dtype<<<1, 256, 0, stream>>>((const u16*)d_in[0], flags);
  convert_inputs<<<3587, 256, 0, stream>>>(
      d_in[0], d_in[1], d_in[3], d_in[5],
      d_in[2], d_in[4], d_in[6], d_in[7], d_in[8],
      ws, flags);

  dim3 g1(32, 8, 3);
  qkv_gemm<<<g1, 256, 0, stream>>>(ws, Qw, Kw, VTw);
  dim3 g2(32, 32);
  attn<<<g2, 256, 0, stream>>>(Qw, Kw, VTw, Ow);
  ln_gather<<<4096, 256, 0, stream>>>(ws, Ow, ws + 7343104, ws + 7344128,
                                      (float*)d_out);
}